// Round 6
// baseline (506.307 us; speedup 1.0000x reference)
//
#include <hip/hip_runtime.h>
#include <hip/hip_cooperative_groups.h>
#include <stdint.h>

namespace cg = cooperative_groups;

typedef __attribute__((ext_vector_type(8))) short short8;
typedef __attribute__((ext_vector_type(4))) float f32x4;
typedef __attribute__((ext_vector_type(4))) uint32_t u32x4;
typedef __attribute__((ext_vector_type(4))) unsigned short u16x4;

#define K_TOP 410

// ws layout (byte offsets)
#define WS_SCALE  5120
#define WS_SHIFT  7168
#define WS_WPART  9216
#define WS_SUB    16384                         // 8192 f32
#define WS_MASK   65536                         // 16384 f32
#define WS_BMAT   131072                        // 4 MB bmat3
#define WS_PSUM   (131072 + 4194304)            // 256 KB
#define WS_PSQ    (131072 + 4194304 + 262144)   // 256 KB
// bmat3: chunk id = (((nt*64+kt)*2+kk)*16 + nn)*64 + g*16 + lr ; 16B chunk =
//   W[nt*256+nn*16+lr][kt*64 + kk*32 + 8g .. +8] as bf16 (ternarized)

__device__ __forceinline__ unsigned short f2bf(float f) {
  uint32_t u = __float_as_uint(f);
  u += 0x7fffu + ((u >> 16) & 1u);   // RTNE
  return (unsigned short)(u >> 16);
}

__device__ __forceinline__ uint32_t pkbf(float a, float b) {
  uint32_t r;
  asm("v_cvt_pk_bf16_f32 %0, %1, %2" : "=v"(r) : "v"(a), "v"(b));
  return r;
}

__global__ __launch_bounds__(512, 2)
void k_fused(const float* __restrict__ x, const float* __restrict__ w,
             const float* __restrict__ posp, const float* __restrict__ negp,
             const float* __restrict__ salw, const float* __restrict__ salb,
             const float* __restrict__ gamma, const float* __restrict__ beta,
             float* __restrict__ out, char* __restrict__ ws) {
  __shared__ __align__(16) unsigned short xs[2][36 * 32 * 8];   // 2 x 18 KB A dbuf
  float* Lf = (float*)&xs[0][0];

  float* scaleA = (float*)(ws + WS_SCALE);
  float* shiftA = (float*)(ws + WS_SHIFT);
  float* wpart  = (float*)(ws + WS_WPART);
  float* sub    = (float*)(ws + WS_SUB);
  float* maskA  = (float*)(ws + WS_MASK);
  unsigned short* bmat3 = (unsigned short*)(ws + WS_BMAT);
  float* psumA  = (float*)(ws + WS_PSUM);
  float* psqA   = (float*)(ws + WS_PSQ);

  int tid = threadIdx.x;
  int lane = tid & 63, wid = tid >> 6;
  int wg = blockIdx.x;
  cg::grid_group grid = cg::this_grid();

  // ================= PHASE A: sub[] + per-block w-max =================
  {
#pragma unroll
    for (int rr = 0; rr < 4; ++rr) {
      int row = wg * 32 + wid * 4 + rr;                 // (b,cin) 0..8191
      const f32x4* rp = (const f32x4*)(x + (size_t)row * 4096);
      float s = 0.f;
#pragma unroll
      for (int i = 0; i < 16; ++i) {
        f32x4 v = rp[lane + i * 64];
        s += fabsf(v.x) + fabsf(v.y) + fabsf(v.z) + fabsf(v.w);
      }
#pragma unroll
      for (int o = 1; o < 64; o <<= 1) s += __shfl_xor(s, o);
      if (lane == 0) sub[row] = s * (1.f / 4096.f);
    }
    const f32x4* wp = (const f32x4*)w + (size_t)wg * 2048;
    float m = 0.f;
#pragma unroll
    for (int i = 0; i < 4; ++i) {
      f32x4 v = wp[tid + i * 512];
      m = fmaxf(m, fmaxf(fmaxf(fabsf(v.x), fabsf(v.y)), fmaxf(fabsf(v.z), fabsf(v.w))));
    }
#pragma unroll
    for (int o = 1; o < 64; o <<= 1) m = fmaxf(m, __shfl_xor(m, o));
    if (lane == 0) Lf[wid] = m;
    __syncthreads();
    if (tid == 0) {
      float mm = Lf[0];
#pragma unroll
      for (int i = 1; i < 8; ++i) mm = fmaxf(mm, Lf[i]);
      wpart[wg] = mm;
    }
    __syncthreads();
  }
  grid.sync();

  // ================= PHASE B: quant -> bmat3, saliency mask =================
  {
    f32x4 wv = ((const f32x4*)wpart)[lane];
    float m = fmaxf(fmaxf(wv.x, wv.y), fmaxf(wv.z, wv.w));
#pragma unroll
    for (int o = 1; o < 64; o <<= 1) m = fmaxf(m, __shfl_xor(m, o));
    float thr = 0.05f * m;
    unsigned short bp = f2bf(*posp), bn = f2bf(*negp);
#pragma unroll
    for (int q = 0; q < 2; ++q) {
      int id = wg * 1024 + tid * 2 + q;
      int lp = id & 63, nn = (id >> 6) & 15, kk = (id >> 10) & 1;
      int kt = (id >> 11) & 63, nt = id >> 17;
      int gq = lp >> 4, lrq = lp & 15;
      int cout = nt * 256 + nn * 16 + lrq;
      const float* src = w + (size_t)cout * 4096 + kt * 64 + kk * 32 + gq * 8;
      f32x4 a = *(const f32x4*)src;
      f32x4 b2 = *(const f32x4*)(src + 4);
      u16x4 q0, q1;
      q0.x = a.x > thr ? bp : (a.x < -thr ? bn : (unsigned short)0);
      q0.y = a.y > thr ? bp : (a.y < -thr ? bn : (unsigned short)0);
      q0.z = a.z > thr ? bp : (a.z < -thr ? bn : (unsigned short)0);
      q0.w = a.w > thr ? bp : (a.w < -thr ? bn : (unsigned short)0);
      q1.x = b2.x > thr ? bp : (b2.x < -thr ? bn : (unsigned short)0);
      q1.y = b2.y > thr ? bp : (b2.y < -thr ? bn : (unsigned short)0);
      q1.z = b2.z > thr ? bp : (b2.z < -thr ? bn : (unsigned short)0);
      q1.w = b2.w > thr ? bp : (b2.w < -thr ? bn : (unsigned short)0);
      ((u16x4*)bmat3)[(size_t)id * 2]     = q0;
      ((u16x4*)bmat3)[(size_t)id * 2 + 1] = q1;
    }
    if (wg < 32) {                                   // saliency + top-k for b = wg
      float* subs = Lf;          // 256
      float* sals = Lf + 256;    // 512
      float* thrp = Lf + 768;
      if (tid < 256) subs[tid] = sub[wg * 256 + tid];
      __syncthreads();
      float acc = salb[tid];
      const f32x4* swp = (const f32x4*)(salw + (size_t)tid * 256);
#pragma unroll 4
      for (int i = 0; i < 64; ++i) {
        f32x4 v = swp[i];
        acc += subs[4 * i] * v.x + subs[4 * i + 1] * v.y +
               subs[4 * i + 2] * v.z + subs[4 * i + 3] * v.w;
      }
      float sal = fabsf(acc);
      sals[tid] = sal;
      __syncthreads();
      int gt = 0, eq = 0;
      for (int j = 0; j < 512; ++j) {
        float v = sals[j];
        gt += (v > sal); eq += (v == sal);
      }
      if (gt < K_TOP && gt + eq >= K_TOP) *thrp = sal;
      __syncthreads();
      maskA[wg * 512 + tid] = (sal > *thrp) ? sal : 0.f;
      __syncthreads();
    }
  }
  grid.sync();

  // ================= PHASE C: implicit-GEMM conv =================
  int nt = wg >> 7, mt = wg & 127;
  int wm = wid >> 1, wn = wid & 1;                   // 4m x 2n waves, tile 64x128
  int g = lane >> 4, lr = lane & 15;
  int b = mt >> 2, OH0 = (mt & 3) * 8;
  const size_t xb = (size_t)b * 256 * 4096;

  int jA = tid & 15, riA = tid >> 4;                 // rows 0..31
  int c2A = riA / 9, rpA = riA - c2A * 9;
  int ihA = 2 * (OH0 + rpA) - 1;
  bool vA0 = (unsigned)ihA < 64u, vA1 = (unsigned)(ihA + 1) < 64u;
  const float* pA = x + xb + (size_t)c2A * 4096 + (long)ihA * 64 + 4 * jA;
  bool hasB = (wid < 4) && (lane < 16);              // rows 32..35
  int riB = 32 + wid, jB = lane & 15;
  int rpB = riB - 27;
  int ihB = 2 * (OH0 + rpB) - 1;
  bool vB0 = (unsigned)ihB < 64u, vB1 = (unsigned)(ihB + 1) < 64u;
  const float* pB = x + xb + (size_t)3 * 4096 + (long)ihB * 64 + 4 * jB;

  f32x4 acc[4][8];
#pragma unroll
  for (int i = 0; i < 4; ++i)
#pragma unroll
    for (int j = 0; j < 8; ++j) acc[i][j] = (f32x4){0.f, 0.f, 0.f, 0.f};

  auto z4 = []() { return (f32x4){0.f, 0.f, 0.f, 0.f}; };
  auto wtask = [&](int buf, int rowidx, int j, f32x4 v0, f32x4 v1) {
    float pw0 = __shfl_up(v0.w, 1);   if (j == 0)  pw0 = 0.f;
    float nx0 = __shfl_down(v0.x, 1); if (j == 15) nx0 = 0.f;
    float pw1 = __shfl_up(v1.w, 1);   if (j == 0)  pw1 = 0.f;
    float nx1 = __shfl_down(v1.x, 1); if (j == 15) nx1 = 0.f;
    uint32_t a0 = pkbf(pw0, v0.x), b0 = pkbf(v0.y, v0.z), c0 = pkbf(v0.w, nx0);
    uint32_t a1 = pkbf(pw1, v1.x), b1 = pkbf(v1.y, v1.z), c1 = pkbf(v1.w, nx1);
    u32x4* dst = (u32x4*)&xs[buf][0];
    dst[rowidx * 32 + j]      = (u32x4){a0, b0, a1, b1};
    dst[rowidx * 32 + 16 + j] = (u32x4){b0, c0, b1, c1};
  };

  const u32x4* bm4 = (const u32x4*)bmat3;
  union UF { u32x4 u; short8 s; };
  UF b0f[8], b1f[8];

  {                                                   // prologue
    f32x4 a0 = vA0 ? *(const f32x4*)pA : z4();
    f32x4 a1 = vA1 ? *(const f32x4*)(pA + 64) : z4();
    f32x4 c0 = z4(), c1 = z4();
    if (hasB) {
      c0 = vB0 ? *(const f32x4*)pB : z4();
      c1 = vB1 ? *(const f32x4*)(pB + 64) : z4();
    }
    int cb = (nt * 64 * 2) * 1024 + (wn * 8) * 64 + lane;
#pragma unroll
    for (int ni = 0; ni < 8; ++ni) b0f[ni].u = bm4[cb + ni * 64];
    wtask(0, riA, jA, a0, a1);
    if (hasB) wtask(0, riB, jB, c0, c1);
    asm volatile("s_waitcnt vmcnt(0) lgkmcnt(0)" ::: "memory");
    __builtin_amdgcn_s_barrier();
    __builtin_amdgcn_sched_barrier(0);
  }

  for (int kt = 0; kt < 64; ++kt) {
    int cur = kt & 1, nxt = cur ^ 1;
    bool pre = (kt < 63);

    f32x4 a0, a1, c0, c1;
    if (pre) {                                        // issue A t+1 loads early
      const float* p0 = pA + (size_t)(kt + 1) * 16384;
      a0 = vA0 ? *(const f32x4*)p0 : z4();
      a1 = vA1 ? *(const f32x4*)(p0 + 64) : z4();
      if (hasB) {
        const float* p1 = pB + (size_t)(kt + 1) * 16384;
        c0 = vB0 ? *(const f32x4*)p1 : z4();
        c1 = vB1 ? *(const f32x4*)(p1 + 64) : z4();
      }
    }
    {                                                 // issue B (kt, kk=1)
      int cb = ((nt * 64 + kt) * 2 + 1) * 1024 + (wn * 8) * 64 + lane;
#pragma unroll
      for (int ni = 0; ni < 8; ++ni) b1f[ni].u = bm4[cb + ni * 64];
    }
    const u32x4* xp4 = (const u32x4*)&xs[cur][0];
    {                                                 // kk = 0
      UF af[4];
#pragma unroll
      for (int mi = 0; mi < 4; ++mi) {
        int rowidx = (g >> 1) * 9 + wm * 2 + (mi >> 1) + (g & 1);
        int ow = ((mi & 1) << 4) + lr;
        af[mi].u = xp4[rowidx * 32 + (ow >> 1) + ((ow & 1) << 4)];
      }
      __builtin_amdgcn_s_setprio(1);
#pragma unroll
      for (int mi = 0; mi < 4; ++mi)
#pragma unroll
        for (int ni = 0; ni < 8; ++ni)
          acc[mi][ni] = __builtin_amdgcn_mfma_f32_16x16x32_bf16(af[mi].s, b0f[ni].s, acc[mi][ni], 0, 0, 0);
      __builtin_amdgcn_s_setprio(0);
    }
    __builtin_amdgcn_s_barrier();
    if (pre) {                                        // issue B (kt+1, kk=0)
      int cb = ((nt * 64 + kt + 1) * 2) * 1024 + (wn * 8) * 64 + lane;
#pragma unroll
      for (int ni = 0; ni < 8; ++ni) b0f[ni].u = bm4[cb + ni * 64];
    }
    {                                                 // kk = 1
      UF af[4];
#pragma unroll
      for (int mi = 0; mi < 4; ++mi) {
        int rowidx = (2 + (g >> 1)) * 9 + wm * 2 + (mi >> 1) + (g & 1);
        int ow = ((mi & 1) << 4) + lr;
        af[mi].u = xp4[rowidx * 32 + (ow >> 1) + ((ow & 1) << 4)];
      }
      __builtin_amdgcn_s_setprio(1);
#pragma unroll
      for (int mi = 0; mi < 4; ++mi)
#pragma unroll
        for (int ni = 0; ni < 8; ++ni)
          acc[mi][ni] = __builtin_amdgcn_mfma_f32_16x16x32_bf16(af[mi].s, b1f[ni].s, acc[mi][ni], 0, 0, 0);
      __builtin_amdgcn_s_setprio(0);
    }
    if (pre) {                                        // write A t+1 into nxt
      wtask(nxt, riA, jA, a0, a1);
      if (hasB) wtask(nxt, riB, jB, c0, c1);
    }
    asm volatile("s_waitcnt lgkmcnt(0)" ::: "memory");
    __builtin_amdgcn_s_barrier();
    __builtin_amdgcn_sched_barrier(0);
  }

  // ---- mask + per-block channel partials ----
  float msk[8];
#pragma unroll
  for (int ni = 0; ni < 8; ++ni)
    msk[ni] = maskA[b * 512 + nt * 256 + wn * 128 + ni * 16 + lr];

  float ps[8], pq[8];
#pragma unroll
  for (int ni = 0; ni < 8; ++ni) {
    ps[ni] = 0.f; pq[ni] = 0.f;
#pragma unroll
    for (int mi = 0; mi < 4; ++mi) {
      f32x4 a = acc[mi][ni] * msk[ni];
      acc[mi][ni] = a;                                // keep masked value for BN apply
      ps[ni] += a.x + a.y + a.z + a.w;
      pq[ni] += a.x * a.x + a.y * a.y + a.z * a.z + a.w * a.w;
    }
  }
#pragma unroll
  for (int ni = 0; ni < 8; ++ni) {
    ps[ni] += __shfl_xor(ps[ni], 16); ps[ni] += __shfl_xor(ps[ni], 32);
    pq[ni] += __shfl_xor(pq[ni], 16); pq[ni] += __shfl_xor(pq[ni], 32);
  }
  __syncthreads();
  if (g == 0) {
#pragma unroll
    for (int ni = 0; ni < 8; ++ni) {
      int ch = wn * 128 + ni * 16 + lr;
      Lf[wm * 256 + ch]        = ps[ni];
      Lf[1024 + wm * 256 + ch] = pq[ni];
    }
  }
  __syncthreads();
  if (tid < 256) {
    float bs = Lf[tid] + Lf[256 + tid] + Lf[512 + tid] + Lf[768 + tid];
    float bq = Lf[1024 + tid] + Lf[1280 + tid] + Lf[1536 + tid] + Lf[1792 + tid];
    psumA[(size_t)(nt * 128 + mt) * 256 + tid] = bs;
    psqA [(size_t)(nt * 128 + mt) * 256 + tid] = bq;
  }
  grid.sync();

  // ---- stage-1 reduce: block wg -> channels 2wg, 2wg+1 ----
  {
    int c = wg * 2 + (tid >> 8);
    int ntc = c >> 8, ch = c & 255, s = tid & 255;
    float v1 = 0.f, v2 = 0.f;
    if (s < 128) {
      v1 = psumA[(size_t)(ntc * 128 + s) * 256 + ch];
      v2 = psqA [(size_t)(ntc * 128 + s) * 256 + ch];
    }
#pragma unroll
    for (int o = 1; o < 64; o <<= 1) { v1 += __shfl_xor(v1, o); v2 += __shfl_xor(v2, o); }
    if (lane == 0) { Lf[2048 + wid] = v1; Lf[2056 + wid] = v2; }
    __syncthreads();
    if ((tid & 255) == 0) {
      int base = (tid >> 8) * 4;
      float S = Lf[2048 + base] + Lf[2049 + base] + Lf[2050 + base] + Lf[2051 + base];
      float Q = Lf[2056 + base] + Lf[2057 + base] + Lf[2058 + base] + Lf[2059 + base];
      float mu = S * (1.f / 32768.f);
      float var = Q * (1.f / 32768.f) - mu * mu;
      float sc = gamma[c] * rsqrtf(var + 1e-5f);
      scaleA[c] = sc;
      shiftA[c] = beta[c] - mu * sc;
    }
  }
  grid.sync();

  // ---- BN apply + LeakyReLU from live accumulators, single store ----
#pragma unroll
  for (int ni = 0; ni < 8; ++ni) {
    int n = nt * 256 + wn * 128 + ni * 16 + lr;
    float sc = scaleA[n], sh = shiftA[n];
    float* op = out + (size_t)b * 524288 + (size_t)n * 1024 + OH0 * 32 + wm * 64 + g * 4;
#pragma unroll
    for (int mi = 0; mi < 4; ++mi) {
      f32x4 v = acc[mi][ni] * sc + sh;
      v.x = v.x > 0.f ? v.x : 0.2f * v.x;
      v.y = v.y > 0.f ? v.y : 0.2f * v.y;
      v.z = v.z > 0.f ? v.z : 0.2f * v.z;
      v.w = v.w > 0.f ? v.w : 0.2f * v.w;
      *(f32x4*)(op + mi * 16) = v;
    }
  }
}

extern "C" void kernel_launch(void* const* d_in, const int* in_sizes, int n_in,
                              void* d_out, int out_size, void* d_ws, size_t ws_size,
                              hipStream_t stream) {
  const float* x     = (const float*)d_in[0];
  const float* w     = (const float*)d_in[1];
  const float* pos   = (const float*)d_in[2];
  const float* neg   = (const float*)d_in[3];
  const float* salw  = (const float*)d_in[4];
  const float* salb  = (const float*)d_in[5];
  const float* gamma = (const float*)d_in[6];
  const float* beta  = (const float*)d_in[7];
  float* out = (float*)d_out;
  char* ws = (char*)d_ws;

  void* args[] = { (void*)&x, (void*)&w, (void*)&pos, (void*)&neg, (void*)&salw,
                   (void*)&salb, (void*)&gamma, (void*)&beta, (void*)&out, (void*)&ws };
  hipLaunchCooperativeKernel((void*)k_fused, dim3(256), dim3(512), args, 0, stream);
}